// Round 5
// baseline (520.470 us; speedup 1.0000x reference)
//
#include <hip/hip_runtime.h>

#define BB 4
#define SS 1024
#define DDIM 512
#define HH 8
#define NR 9
#define EPSV 1e-6f

typedef __attribute__((ext_vector_type(8))) short bf16x8;
typedef __attribute__((ext_vector_type(4))) short short4v;
typedef __attribute__((ext_vector_type(4))) float f32x4;

struct HL { short h; short l; };

__device__ inline float bfv(short h) {
    union { unsigned u; float f; } b; b.u = ((unsigned)(unsigned short)h) << 16; return b.f;
}
__device__ inline HL split2(float x) {
    union { float f; unsigned u; } a; a.f = x;
    unsigned short hu = (unsigned short)(a.u >> 16);
    union { unsigned u; float f; } b; b.u = ((unsigned)hu) << 16;
    float r = x - b.f;
    union { float f; unsigned u; } c; c.f = r;
    HL o; o.h = (short)hu; o.l = (short)(c.u >> 16);
    return o;
}

// ---------- LayerNorm(q) -> split bf16 hi/lo ----------
__global__ __launch_bounds__(128) void ln_split(const float* __restrict__ q,
                                                const float* __restrict__ g,
                                                const float* __restrict__ b,
                                                short* __restrict__ yh,
                                                short* __restrict__ yl) {
    int row = blockIdx.x;
    const float* x = q + (size_t)row * DDIM;
    int t = threadIdx.x;
    float4 v = ((const float4*)x)[t];
    float s  = v.x + v.y + v.z + v.w;
    float ss = v.x*v.x + v.y*v.y + v.z*v.z + v.w*v.w;
    __shared__ float rs[128], rss[128];
    rs[t] = s; rss[t] = ss; __syncthreads();
    for (int o = 64; o > 0; o >>= 1) {
        if (t < o) { rs[t] += rs[t+o]; rss[t] += rss[t+o]; }
        __syncthreads();
    }
    float mu  = rs[0] * (1.0f/DDIM);
    float var = rss[0] * (1.0f/DDIM) - mu*mu;
    float inv = rsqrtf(var + EPSV);
    float4 gg = ((const float4*)g)[t];
    float4 bb = ((const float4*)b)[t];
    float o0 = (v.x-mu)*inv*gg.x + bb.x;
    float o1 = (v.y-mu)*inv*gg.y + bb.y;
    float o2 = (v.z-mu)*inv*gg.z + bb.z;
    float o3 = (v.w-mu)*inv*gg.w + bb.w;
    short4v h4, l4;
    HL t0 = split2(o0); h4[0] = t0.h; l4[0] = t0.l;
    HL t1 = split2(o1); h4[1] = t1.h; l4[1] = t1.l;
    HL t2 = split2(o2); h4[2] = t2.h; l4[2] = t2.l;
    HL t3 = split2(o3); h4[3] = t3.h; l4[3] = t3.l;
    *(short4v*)&yh[(size_t)row*DDIM + t*4] = h4;
    *(short4v*)&yl[(size_t)row*DDIM + t*4] = l4;
}

// ---------- split fp32 array -> bf16 hi/lo ----------
__global__ __launch_bounds__(256) void split_x(const float* __restrict__ x,
                                               short* __restrict__ xh,
                                               short* __restrict__ xl) {
    int i = blockIdx.x*256 + threadIdx.x;   // one float4 per thread, exact cover
    float4 v = ((const float4*)x)[i];
    short4v h4, l4;
    HL t0 = split2(v.x); h4[0] = t0.h; l4[0] = t0.l;
    HL t1 = split2(v.y); h4[1] = t1.h; l4[1] = t1.l;
    HL t2 = split2(v.z); h4[2] = t2.h; l4[2] = t2.l;
    HL t3 = split2(v.w); h4[3] = t3.h; l4[3] = t3.l;
    *(short4v*)&xh[(size_t)i*4] = h4;
    *(short4v*)&xl[(size_t)i*4] = l4;
}

// ---------- W [k][n] -> WT [n][k] bf16 hi/lo ----------
__global__ __launch_bounds__(256) void transW(const float* __restrict__ W,
                                              short* __restrict__ wth,
                                              short* __restrict__ wtl) {
    __shared__ float T[64][65];
    int n0 = blockIdx.x*64, k0 = blockIdx.y*64;
    int t = threadIdx.x;
    int kr = t >> 4, nc = (t & 15)*4;
#pragma unroll
    for (int i = 0; i < 4; ++i) {
        float4 v = *(const float4*)&W[(size_t)(k0 + kr + i*16)*DDIM + n0 + nc];
        T[nc+0][kr+i*16] = v.x;
        T[nc+1][kr+i*16] = v.y;
        T[nc+2][kr+i*16] = v.z;
        T[nc+3][kr+i*16] = v.w;
    }
    __syncthreads();
    int nr = t >> 2, kq = (t & 3)*16;
    short h8[16], l8[16];
#pragma unroll
    for (int j = 0; j < 16; ++j) {
        HL tt = split2(T[nr][kq+j]); h8[j] = tt.h; l8[j] = tt.l;
    }
    size_t base = (size_t)(n0+nr)*DDIM + k0 + kq;
#pragma unroll
    for (int j = 0; j < 2; ++j) {
        bf16x8 hv, lv;
#pragma unroll
        for (int e = 0; e < 8; ++e) { hv[e] = h8[j*8+e]; lv[e] = l8[j*8+e]; }
        *(bf16x8*)&wth[base + j*8] = hv;
        *(bf16x8*)&wtl[base + j*8] = lv;
    }
}

// ---------- split-bf16 MFMA GEMM: C[4096x512] = A[4096x512] . BT[512x512]^T ----------
// MODE 0: head-layout bf16 hi/lo out (qh/kh), scaled
// MODE 2: vhT layout [B,H,64,S] bf16 hi/lo out
// MODE 3: fp32 out + residual
template<int MODE>
__global__ __launch_bounds__(256) void mm_gemm(const short* __restrict__ Ahi,
                                               const short* __restrict__ Alo,
                                               const short* __restrict__ Bhi,
                                               const short* __restrict__ Blo,
                                               const float* __restrict__ res,
                                               short* __restrict__ o_hi,
                                               short* __restrict__ o_lo,
                                               float* __restrict__ o_f,
                                               float scale) {
    int n0 = blockIdx.x * 64, m0 = blockIdx.y * 64;
    int tid = threadIdx.x;
    int lane = tid & 63, w = tid >> 6;
    int wr = w >> 1, wc = w & 1;
    int r = lane & 15, ko = (lane >> 4) * 8;
    f32x4 acc[2][2] = {};
    int arow0 = m0 + wr*32 + r;
    int brow0 = n0 + wc*32 + r;
    for (int k0 = 0; k0 < 512; k0 += 32) {
        bf16x8 ah[2], al[2], bh[2], bl[2];
#pragma unroll
        for (int i = 0; i < 2; ++i) {
            size_t aoff = (size_t)(arow0 + i*16)*512 + k0 + ko;
            ah[i] = *(const bf16x8*)&Ahi[aoff];
            al[i] = *(const bf16x8*)&Alo[aoff];
            size_t boff = (size_t)(brow0 + i*16)*512 + k0 + ko;
            bh[i] = *(const bf16x8*)&Bhi[boff];
            bl[i] = *(const bf16x8*)&Blo[boff];
        }
#pragma unroll
        for (int i = 0; i < 2; ++i)
#pragma unroll
            for (int j = 0; j < 2; ++j) {
                acc[i][j] = __builtin_amdgcn_mfma_f32_16x16x32_bf16(ah[i], bh[j], acc[i][j], 0, 0, 0);
                acc[i][j] = __builtin_amdgcn_mfma_f32_16x16x32_bf16(ah[i], bl[j], acc[i][j], 0, 0, 0);
                acc[i][j] = __builtin_amdgcn_mfma_f32_16x16x32_bf16(al[i], bh[j], acc[i][j], 0, 0, 0);
            }
    }
    int rb = (lane >> 4) * 4;
    int cf = lane & 15;
#pragma unroll
    for (int i = 0; i < 2; ++i)
#pragma unroll
        for (int j = 0; j < 2; ++j)
#pragma unroll
            for (int rr = 0; rr < 4; ++rr) {
                int m = m0 + wr*32 + i*16 + rb + rr;
                int n = n0 + wc*32 + j*16 + cf;
                float v = acc[i][j][rr] * scale;
                if (MODE == 3) {
                    o_f[(size_t)m*512 + n] = v + res[(size_t)m*512 + n];
                } else {
                    HL tt = split2(v);
                    int b = m >> 10, s = m & 1023;
                    int hh = n >> 6, d = n & 63;
                    size_t off;
                    if (MODE == 2) off = ((size_t)((b*HH + hh)*64 + d))*SS + s;
                    else           off = ((size_t)((b*HH + hh)*SS + s))*64 + d;
                    o_hi[off] = tt.h;
                    o_lo[off] = tt.l;
                }
            }
}

// ---------- qdr = qh . Wrpr -> [B,H,S,9] fp32 ----------
__global__ __launch_bounds__(256) void qdr_kernel(const short* __restrict__ qhi,
                                                  const short* __restrict__ qlo,
                                                  const float* __restrict__ Wrpr,
                                                  float* __restrict__ qdr) {
    __shared__ float w[64*NR];
    int t = threadIdx.x;
    for (int i = t; i < 64*NR; i += 256) w[i] = Wrpr[i];
    __syncthreads();
    int row = blockIdx.x*256 + t;           // 32768 rows
    const short* qh = qhi + (size_t)row*64;
    const short* ql = qlo + (size_t)row*64;
    float acc[NR] = {};
#pragma unroll
    for (int d4 = 0; d4 < 16; ++d4) {
        short4v h4 = *(const short4v*)&qh[d4*4];
        short4v l4 = *(const short4v*)&ql[d4*4];
#pragma unroll
        for (int j = 0; j < 4; ++j) {
            float x = bfv(h4[j]) + bfv(l4[j]);
            const float* wr2 = &w[(d4*4+j)*NR];
#pragma unroll
            for (int p = 0; p < NR; ++p) acc[p] += x * wr2[p];
        }
    }
#pragma unroll
    for (int p = 0; p < NR; ++p) qdr[(size_t)row*NR + p] = acc[p];
}

// ---------- QK^T + rpr bias -> logits ----------
__global__ __launch_bounds__(256) void qk_mfma(const short* __restrict__ qhi,
                                               const short* __restrict__ qlo,
                                               const short* __restrict__ khi,
                                               const short* __restrict__ klo,
                                               const float* __restrict__ qdr,
                                               const int* __restrict__ dist,
                                               float* __restrict__ attn) {
    __shared__ float qd[64*NR];
    int bh = blockIdx.z, b = bh >> 3;
    int q0 = blockIdx.y*64, k0 = blockIdx.x*64;
    int tid = threadIdx.x;
    for (int i = tid; i < 64*NR; i += 256) qd[i] = qdr[((size_t)bh*SS + q0)*NR + i];
    int lane = tid & 63, w = tid >> 6;
    int wr = w >> 1, wc = w & 1;
    int r = lane & 15, ko = (lane >> 4)*8;
    const short* Aq_h = qhi + (size_t)bh*SS*64;
    const short* Aq_l = qlo + (size_t)bh*SS*64;
    const short* Bk_h = khi + (size_t)bh*SS*64;
    const short* Bk_l = klo + (size_t)bh*SS*64;
    f32x4 acc[2][2] = {};
#pragma unroll
    for (int ks = 0; ks < 64; ks += 32) {
        bf16x8 ah[2], al[2], bh2[2], bl2[2];
#pragma unroll
        for (int i = 0; i < 2; ++i) {
            size_t aoff = (size_t)(q0 + wr*32 + i*16 + r)*64 + ks + ko;
            ah[i] = *(const bf16x8*)&Aq_h[aoff];
            al[i] = *(const bf16x8*)&Aq_l[aoff];
            size_t boff = (size_t)(k0 + wc*32 + i*16 + r)*64 + ks + ko;
            bh2[i] = *(const bf16x8*)&Bk_h[boff];
            bl2[i] = *(const bf16x8*)&Bk_l[boff];
        }
#pragma unroll
        for (int i = 0; i < 2; ++i)
#pragma unroll
            for (int j = 0; j < 2; ++j) {
                acc[i][j] = __builtin_amdgcn_mfma_f32_16x16x32_bf16(ah[i], bh2[j], acc[i][j], 0, 0, 0);
                acc[i][j] = __builtin_amdgcn_mfma_f32_16x16x32_bf16(ah[i], bl2[j], acc[i][j], 0, 0, 0);
                acc[i][j] = __builtin_amdgcn_mfma_f32_16x16x32_bf16(al[i], bh2[j], acc[i][j], 0, 0, 0);
            }
    }
    __syncthreads();
    int rb = (lane >> 4)*4, cf = lane & 15;
#pragma unroll
    for (int i = 0; i < 2; ++i)
#pragma unroll
        for (int j = 0; j < 2; ++j)
#pragma unroll
            for (int rr = 0; rr < 4; ++rr) {
                int qq = q0 + wr*32 + i*16 + rb + rr;
                int kk = k0 + wc*32 + j*16 + cf;
                int dd = dist[((size_t)b*SS + qq)*SS + kk];
                if (dd > 8) dd = 8;
                attn[((size_t)bh*SS + qq)*SS + kk] = acc[i][j][rr] + qd[(qq - q0)*NR + dd];
            }
}

// ---------- fused softmax + PV ----------
// One block per (bh, 64 q-rows). Pass 1: online (m,s) over the row's logits.
// Pass 2: re-read (L2-hot), write normalized attn, feed PV MFMA.
// Lanes {r, r+16, r+32, r+48} of a wave jointly own one q-row (k-interleaved by 8).
__global__ __launch_bounds__(256) void pv_fused(float* __restrict__ attn,
                                                const short* __restrict__ vThi,
                                                const short* __restrict__ vTlo,
                                                short* __restrict__ pv_hi,
                                                short* __restrict__ pv_lo) {
    int bh = blockIdx.y, q0 = blockIdx.x*64;
    int tid = threadIdx.x, lane = tid & 63, w = tid >> 6;
    int r = lane & 15, ko = (lane >> 4)*8;
    float* Arow = attn + ((size_t)bh*SS + q0 + w*16 + r)*SS;
    const short* Vh = vThi + (size_t)bh*64*SS;
    const short* Vl = vTlo + (size_t)bh*64*SS;

    // pass 1: per-lane online max/sum over this lane's 256 of 1024 logits
    float m = -1e30f, s = 0.f;
    for (int kb = 0; kb < SS; kb += 32) {
        f32x4 p0 = *(const f32x4*)&Arow[kb + ko];
        f32x4 p1 = *(const f32x4*)&Arow[kb + ko + 4];
        float t = fmaxf(fmaxf(fmaxf(p0[0],p0[1]), fmaxf(p0[2],p0[3])),
                        fmaxf(fmaxf(p1[0],p1[1]), fmaxf(p1[2],p1[3])));
        if (t > m) { s *= expf(m - t); m = t; }
        s += expf(p0[0]-m) + expf(p0[1]-m) + expf(p0[2]-m) + expf(p0[3]-m)
           + expf(p1[0]-m) + expf(p1[1]-m) + expf(p1[2]-m) + expf(p1[3]-m);
    }
    // combine the 4 lanes sharing this row (xor bits 4,5)
#pragma unroll
    for (int mask = 16; mask <= 32; mask <<= 1) {
        float m2 = __shfl_xor(m, mask);
        float s2 = __shfl_xor(s, mask);
        float mn = fmaxf(m, m2);
        s = s*expf(m - mn) + s2*expf(m2 - mn);
        m = mn;
    }
    float inv = 1.0f / s;

    // pass 2: normalize, write attn, PV MFMA
    f32x4 acc[4] = {};
    for (int kb = 0; kb < SS; kb += 32) {
        f32x4 p0 = *(const f32x4*)&Arow[kb + ko];
        f32x4 p1 = *(const f32x4*)&Arow[kb + ko + 4];
        p0[0] = expf(p0[0]-m)*inv; p0[1] = expf(p0[1]-m)*inv;
        p0[2] = expf(p0[2]-m)*inv; p0[3] = expf(p0[3]-m)*inv;
        p1[0] = expf(p1[0]-m)*inv; p1[1] = expf(p1[1]-m)*inv;
        p1[2] = expf(p1[2]-m)*inv; p1[3] = expf(p1[3]-m)*inv;
        *(f32x4*)&Arow[kb + ko]     = p0;
        *(f32x4*)&Arow[kb + ko + 4] = p1;
        bf16x8 ah, al;
        HL s0 = split2(p0[0]); ah[0] = s0.h; al[0] = s0.l;
        HL s1 = split2(p0[1]); ah[1] = s1.h; al[1] = s1.l;
        HL s2 = split2(p0[2]); ah[2] = s2.h; al[2] = s2.l;
        HL s3 = split2(p0[3]); ah[3] = s3.h; al[3] = s3.l;
        HL s4 = split2(p1[0]); ah[4] = s4.h; al[4] = s4.l;
        HL s5 = split2(p1[1]); ah[5] = s5.h; al[5] = s5.l;
        HL s6 = split2(p1[2]); ah[6] = s6.h; al[6] = s6.l;
        HL s7 = split2(p1[3]); ah[7] = s7.h; al[7] = s7.l;
#pragma unroll
        for (int j = 0; j < 4; ++j) {
            size_t voff = (size_t)(j*16 + r)*SS + kb + ko;
            bf16x8 vh = *(const bf16x8*)&Vh[voff];
            bf16x8 vl = *(const bf16x8*)&Vl[voff];
            acc[j] = __builtin_amdgcn_mfma_f32_16x16x32_bf16(ah, vh, acc[j], 0, 0, 0);
            acc[j] = __builtin_amdgcn_mfma_f32_16x16x32_bf16(ah, vl, acc[j], 0, 0, 0);
            acc[j] = __builtin_amdgcn_mfma_f32_16x16x32_bf16(al, vh, acc[j], 0, 0, 0);
        }
    }
    int b = bh >> 3, h = bh & 7;
    int rb = (lane >> 4)*4, cf = lane & 15;
#pragma unroll
    for (int j = 0; j < 4; ++j)
#pragma unroll
        for (int rr = 0; rr < 4; ++rr) {
            int s2 = q0 + w*16 + rb + rr;
            int d = j*16 + cf;
            HL tt = split2(acc[j][rr]);
            size_t off = ((size_t)(b*SS + s2))*512 + h*64 + d;
            pv_hi[off] = tt.h; pv_lo[off] = tt.l;
        }
}

extern "C" void kernel_launch(void* const* d_in, const int* in_sizes, int n_in,
                              void* d_out, int out_size, void* d_ws, size_t ws_size,
                              hipStream_t stream) {
    const float* q    = (const float*)d_in[0];
    const float* k    = (const float*)d_in[1];
    const float* v    = (const float*)d_in[2];
    const int*   dist = (const int*)d_in[3];
    const float* Wq   = (const float*)d_in[4];
    const float* Wk   = (const float*)d_in[5];
    const float* Wv   = (const float*)d_in[6];
    const float* Wrpr = (const float*)d_in[7];
    const float* Wo   = (const float*)d_in[8];
    const float* ln_g = (const float*)d_in[9];
    const float* ln_b = (const float*)d_in[10];

    float* out  = (float*)d_out;                       // [B,S,D]
    float* attn = out + (size_t)BB*SS*DDIM;            // [B,H,S,S]

    const size_t NB = (size_t)BB*SS*DDIM;              // 2,097,152 elements
    short* p = (short*)d_ws;
    short* qn_hi = p;            p += NB;
    short* qn_lo = p;            p += NB;
    short* kx_hi = p;            p += NB;
    short* kx_lo = p;            p += NB;
    short* vx_hi = p;            p += NB;
    short* vx_lo = p;            p += NB;
    short* qh_hi = p;            p += NB;
    short* qh_lo = p;            p += NB;
    short* kh_hi = p;            p += NB;
    short* kh_lo = p;            p += NB;
    short* vT_hi = p;            p += NB;
    short* vT_lo = p;            p += NB;
    short* WqT_h = p;            p += 262144;
    short* WqT_l = p;            p += 262144;
    short* WkT_h = p;            p += 262144;
    short* WkT_l = p;            p += 262144;
    short* WvT_h = p;            p += 262144;
    short* WvT_l = p;            p += 262144;
    short* WoT_h = p;            p += 262144;
    short* WoT_l = p;            p += 262144;
    float* qdrp  = (float*)p;
    short* pv_hi = qn_hi;        // alias: qn dead after Q-projection
    short* pv_lo = qn_lo;

    // 1. LayerNorm(q) -> split
    ln_split<<<BB*SS, 128, 0, stream>>>(q, ln_g, ln_b, qn_hi, qn_lo);

    // 2. split k, v
    split_x<<<2048, 256, 0, stream>>>(k, kx_hi, kx_lo);
    split_x<<<2048, 256, 0, stream>>>(v, vx_hi, vx_lo);

    // 3. transpose+split weights -> [n][k]
    transW<<<dim3(8,8), 256, 0, stream>>>(Wq, WqT_h, WqT_l);
    transW<<<dim3(8,8), 256, 0, stream>>>(Wk, WkT_h, WkT_l);
    transW<<<dim3(8,8), 256, 0, stream>>>(Wv, WvT_h, WvT_l);
    transW<<<dim3(8,8), 256, 0, stream>>>(Wo, WoT_h, WoT_l);

    // 4. projections (MFMA, split-bf16); 1/sqrt(dk) folded into qh
    dim3 gp(8, 64);
    mm_gemm<0><<<gp, 256, 0, stream>>>(qn_hi, qn_lo, WqT_h, WqT_l, nullptr, qh_hi, qh_lo, nullptr, 0.125f);
    mm_gemm<0><<<gp, 256, 0, stream>>>(kx_hi, kx_lo, WkT_h, WkT_l, nullptr, kh_hi, kh_lo, nullptr, 1.0f);
    mm_gemm<2><<<gp, 256, 0, stream>>>(vx_hi, vx_lo, WvT_h, WvT_l, nullptr, vT_hi, vT_lo, nullptr, 1.0f);

    // 5. qdr
    qdr_kernel<<<128, 256, 0, stream>>>(qh_hi, qh_lo, Wrpr, qdrp);

    // 6. QK^T + bias -> logits (written to attn region of d_out)
    qk_mfma<<<dim3(16,16,32), 256, 0, stream>>>(qh_hi, qh_lo, kh_hi, kh_lo, qdrp, dist, attn);

    // 7. fused softmax + PV (normalizes attn in place, writes pv bf16 hi/lo)
    pv_fused<<<dim3(16,32), 256, 0, stream>>>(attn, vT_hi, vT_lo, pv_hi, pv_lo);

    // 8. output projection + residual
    mm_gemm<3><<<gp, 256, 0, stream>>>(pv_hi, pv_lo, WoT_h, WoT_l, q, nullptr, nullptr, out, 1.0f);
}

// Round 6
// 454.642 us; speedup vs baseline: 1.1448x; 1.1448x over previous
//
#include <hip/hip_runtime.h>

#define BB 4
#define SS 1024
#define DDIM 512
#define HH 8
#define NR 9
#define QB 16
#define EPSV 1e-6f

typedef __attribute__((ext_vector_type(8))) short bf16x8;
typedef __attribute__((ext_vector_type(4))) short short4v;
typedef __attribute__((ext_vector_type(4))) float f32x4;

struct HL { short h; short l; };

__device__ inline float bfv(short h) {
    union { unsigned u; float f; } b; b.u = ((unsigned)(unsigned short)h) << 16; return b.f;
}
__device__ inline HL split2(float x) {
    union { float f; unsigned u; } a; a.f = x;
    unsigned short hu = (unsigned short)(a.u >> 16);
    union { unsigned u; float f; } b; b.u = ((unsigned)hu) << 16;
    float r = x - b.f;
    union { float f; unsigned u; } c; c.f = r;
    HL o; o.h = (short)hu; o.l = (short)(c.u >> 16);
    return o;
}

// ---------- LayerNorm(q) -> split bf16 hi/lo ----------
__global__ __launch_bounds__(128) void ln_split(const float* __restrict__ q,
                                                const float* __restrict__ g,
                                                const float* __restrict__ b,
                                                short* __restrict__ yh,
                                                short* __restrict__ yl) {
    int row = blockIdx.x;
    const float* x = q + (size_t)row * DDIM;
    int t = threadIdx.x;
    float4 v = ((const float4*)x)[t];
    float s  = v.x + v.y + v.z + v.w;
    float ss = v.x*v.x + v.y*v.y + v.z*v.z + v.w*v.w;
    __shared__ float rs[128], rss[128];
    rs[t] = s; rss[t] = ss; __syncthreads();
    for (int o = 64; o > 0; o >>= 1) {
        if (t < o) { rs[t] += rs[t+o]; rss[t] += rss[t+o]; }
        __syncthreads();
    }
    float mu  = rs[0] * (1.0f/DDIM);
    float var = rss[0] * (1.0f/DDIM) - mu*mu;
    float inv = rsqrtf(var + EPSV);
    float4 gg = ((const float4*)g)[t];
    float4 bb = ((const float4*)b)[t];
    float o0 = (v.x-mu)*inv*gg.x + bb.x;
    float o1 = (v.y-mu)*inv*gg.y + bb.y;
    float o2 = (v.z-mu)*inv*gg.z + bb.z;
    float o3 = (v.w-mu)*inv*gg.w + bb.w;
    short4v h4, l4;
    HL t0 = split2(o0); h4[0] = t0.h; l4[0] = t0.l;
    HL t1 = split2(o1); h4[1] = t1.h; l4[1] = t1.l;
    HL t2 = split2(o2); h4[2] = t2.h; l4[2] = t2.l;
    HL t3 = split2(o3); h4[3] = t3.h; l4[3] = t3.l;
    *(short4v*)&yh[(size_t)row*DDIM + t*4] = h4;
    *(short4v*)&yl[(size_t)row*DDIM + t*4] = l4;
}

// ---------- split fp32 array -> bf16 hi/lo ----------
__global__ __launch_bounds__(256) void split_x(const float* __restrict__ x,
                                               short* __restrict__ xh,
                                               short* __restrict__ xl) {
    int i = blockIdx.x*256 + threadIdx.x;
    float4 v = ((const float4*)x)[i];
    short4v h4, l4;
    HL t0 = split2(v.x); h4[0] = t0.h; l4[0] = t0.l;
    HL t1 = split2(v.y); h4[1] = t1.h; l4[1] = t1.l;
    HL t2 = split2(v.z); h4[2] = t2.h; l4[2] = t2.l;
    HL t3 = split2(v.w); h4[3] = t3.h; l4[3] = t3.l;
    *(short4v*)&xh[(size_t)i*4] = h4;
    *(short4v*)&xl[(size_t)i*4] = l4;
}

// ---------- W [k][n] -> WT [n][k] bf16 hi/lo ----------
__global__ __launch_bounds__(256) void transW(const float* __restrict__ W,
                                              short* __restrict__ wth,
                                              short* __restrict__ wtl) {
    __shared__ float T[64][65];
    int n0 = blockIdx.x*64, k0 = blockIdx.y*64;
    int t = threadIdx.x;
    int kr = t >> 4, nc = (t & 15)*4;
#pragma unroll
    for (int i = 0; i < 4; ++i) {
        float4 v = *(const float4*)&W[(size_t)(k0 + kr + i*16)*DDIM + n0 + nc];
        T[nc+0][kr+i*16] = v.x;
        T[nc+1][kr+i*16] = v.y;
        T[nc+2][kr+i*16] = v.z;
        T[nc+3][kr+i*16] = v.w;
    }
    __syncthreads();
    int nr = t >> 2, kq = (t & 3)*16;
    short h8[16], l8[16];
#pragma unroll
    for (int j = 0; j < 16; ++j) {
        HL tt = split2(T[nr][kq+j]); h8[j] = tt.h; l8[j] = tt.l;
    }
    size_t base = (size_t)(n0+nr)*DDIM + k0 + kq;
#pragma unroll
    for (int j = 0; j < 2; ++j) {
        bf16x8 hv, lv;
#pragma unroll
        for (int e = 0; e < 8; ++e) { hv[e] = h8[j*8+e]; lv[e] = l8[j*8+e]; }
        *(bf16x8*)&wth[base + j*8] = hv;
        *(bf16x8*)&wtl[base + j*8] = lv;
    }
}

// ---------- split-bf16 MFMA GEMM ----------
template<int MODE>
__global__ __launch_bounds__(256) void mm_gemm(const short* __restrict__ Ahi,
                                               const short* __restrict__ Alo,
                                               const short* __restrict__ Bhi,
                                               const short* __restrict__ Blo,
                                               const float* __restrict__ res,
                                               short* __restrict__ o_hi,
                                               short* __restrict__ o_lo,
                                               float* __restrict__ o_f,
                                               float scale) {
    int n0 = blockIdx.x * 64, m0 = blockIdx.y * 64;
    int tid = threadIdx.x;
    int lane = tid & 63, w = tid >> 6;
    int wr = w >> 1, wc = w & 1;
    int r = lane & 15, ko = (lane >> 4) * 8;
    f32x4 acc[2][2] = {};
    int arow0 = m0 + wr*32 + r;
    int brow0 = n0 + wc*32 + r;
    for (int k0 = 0; k0 < 512; k0 += 32) {
        bf16x8 ah[2], al[2], bh[2], bl[2];
#pragma unroll
        for (int i = 0; i < 2; ++i) {
            size_t aoff = (size_t)(arow0 + i*16)*512 + k0 + ko;
            ah[i] = *(const bf16x8*)&Ahi[aoff];
            al[i] = *(const bf16x8*)&Alo[aoff];
            size_t boff = (size_t)(brow0 + i*16)*512 + k0 + ko;
            bh[i] = *(const bf16x8*)&Bhi[boff];
            bl[i] = *(const bf16x8*)&Blo[boff];
        }
#pragma unroll
        for (int i = 0; i < 2; ++i)
#pragma unroll
            for (int j = 0; j < 2; ++j) {
                acc[i][j] = __builtin_amdgcn_mfma_f32_16x16x32_bf16(ah[i], bh[j], acc[i][j], 0, 0, 0);
                acc[i][j] = __builtin_amdgcn_mfma_f32_16x16x32_bf16(ah[i], bl[j], acc[i][j], 0, 0, 0);
                acc[i][j] = __builtin_amdgcn_mfma_f32_16x16x32_bf16(al[i], bh[j], acc[i][j], 0, 0, 0);
            }
    }
    int rb = (lane >> 4) * 4;
    int cf = lane & 15;
#pragma unroll
    for (int i = 0; i < 2; ++i)
#pragma unroll
        for (int j = 0; j < 2; ++j)
#pragma unroll
            for (int rr = 0; rr < 4; ++rr) {
                int m = m0 + wr*32 + i*16 + rb + rr;
                int n = n0 + wc*32 + j*16 + cf;
                float v = acc[i][j][rr] * scale;
                if (MODE == 3) {
                    o_f[(size_t)m*512 + n] = v + res[(size_t)m*512 + n];
                } else {
                    HL tt = split2(v);
                    int b = m >> 10, s = m & 1023;
                    int hh = n >> 6, d = n & 63;
                    size_t off;
                    if (MODE == 2) off = ((size_t)((b*HH + hh)*64 + d))*SS + s;
                    else           off = ((size_t)((b*HH + hh)*SS + s))*64 + d;
                    o_hi[off] = tt.h;
                    o_lo[off] = tt.l;
                }
            }
}

// ---------- qdr = qh . Wrpr -> [B,H,S,9] fp32 ----------
__global__ __launch_bounds__(256) void qdr_kernel(const short* __restrict__ qhi,
                                                  const short* __restrict__ qlo,
                                                  const float* __restrict__ Wrpr,
                                                  float* __restrict__ qdr) {
    __shared__ float w[64*NR];
    int t = threadIdx.x;
    for (int i = t; i < 64*NR; i += 256) w[i] = Wrpr[i];
    __syncthreads();
    int row = blockIdx.x*256 + t;
    const short* qh = qhi + (size_t)row*64;
    const short* ql = qlo + (size_t)row*64;
    float acc[NR] = {};
#pragma unroll
    for (int d4 = 0; d4 < 16; ++d4) {
        short4v h4 = *(const short4v*)&qh[d4*4];
        short4v l4 = *(const short4v*)&ql[d4*4];
#pragma unroll
        for (int j = 0; j < 4; ++j) {
            float x = bfv(h4[j]) + bfv(l4[j]);
            const float* wr2 = &w[(d4*4+j)*NR];
#pragma unroll
            for (int p = 0; p < NR; ++p) acc[p] += x * wr2[p];
        }
    }
#pragma unroll
    for (int p = 0; p < NR; ++p) qdr[(size_t)row*NR + p] = acc[p];
}

// ---------- fused QK^T + bias + softmax + attn-write + PV ----------
// Block = 256 threads (4 waves), owns QB=16 q-rows x all 1024 k-cols of one (b,h).
// Logits live in LDS S_T[col][row] (stride 17 words: all hot patterns <=2-way conflict).
// Phase A: QK MFMA (wave w covers cols w*256..): C col=lane&15 -> k-col, row=(lane>>4)*4+rr -> q-row.
// Phase B: 16 threads/row: bias gather (int4 dist, coalesced), online softmax,
//          normalized attn written once (mandatory output traffic only).
// Phase C: PV MFMA from LDS P (unnormalized), epilogue scales by 1/rowsum.
__global__ __launch_bounds__(256, 2) void fused_attn(
        const short* __restrict__ qhi, const short* __restrict__ qlo,
        const short* __restrict__ khi, const short* __restrict__ klo,
        const short* __restrict__ vThi, const short* __restrict__ vTlo,
        const float* __restrict__ qdr,
        const int* __restrict__ dist,
        float* __restrict__ attn,
        short* __restrict__ pv_hi, short* __restrict__ pv_lo) {
    __shared__ float S_T[SS][QB+1];      // 1024 x 17 words = 68 KB
    __shared__ float qd[QB][NR];
    __shared__ float inv_s[QB];
    int bh = blockIdx.y, b = bh >> 3, h = bh & 7;
    int q0 = blockIdx.x * QB;
    int tid = threadIdx.x, lane = tid & 63, w = tid >> 6;
    int r = lane & 15, g = lane >> 4, ko = g*8;

    if (tid < QB*NR) qd[tid/NR][tid%NR] = qdr[((size_t)bh*SS + q0)*NR + tid];

    // ---- Phase A: QK^T ----
    const short* Qh = qhi + (size_t)bh*SS*64;
    const short* Ql = qlo + (size_t)bh*SS*64;
    const short* Kh = khi + (size_t)bh*SS*64;
    const short* Kl = klo + (size_t)bh*SS*64;
    f32x4 acc[16];
#pragma unroll
    for (int t2 = 0; t2 < 16; ++t2) acc[t2] = (f32x4){0.f,0.f,0.f,0.f};
#pragma unroll
    for (int ks = 0; ks < 64; ks += 32) {
        bf16x8 ah = *(const bf16x8*)&Qh[(size_t)(q0+r)*64 + ks + ko];
        bf16x8 al = *(const bf16x8*)&Ql[(size_t)(q0+r)*64 + ks + ko];
#pragma unroll
        for (int ct = 0; ct < 16; ++ct) {
            int kc = w*256 + ct*16 + r;
            bf16x8 bh2 = *(const bf16x8*)&Kh[(size_t)kc*64 + ks + ko];
            bf16x8 bl2 = *(const bf16x8*)&Kl[(size_t)kc*64 + ks + ko];
            acc[ct] = __builtin_amdgcn_mfma_f32_16x16x32_bf16(ah, bh2, acc[ct], 0, 0, 0);
            acc[ct] = __builtin_amdgcn_mfma_f32_16x16x32_bf16(ah, bl2, acc[ct], 0, 0, 0);
            acc[ct] = __builtin_amdgcn_mfma_f32_16x16x32_bf16(al, bh2, acc[ct], 0, 0, 0);
        }
    }
#pragma unroll
    for (int ct = 0; ct < 16; ++ct)
#pragma unroll
        for (int rr = 0; rr < 4; ++rr)
            S_T[w*256 + ct*16 + r][g*4 + rr] = acc[ct][rr];
    __syncthreads();

    // ---- Phase B: bias + softmax + attn write ----
    int row = tid >> 4, c16 = tid & 15;
    const int* drow = &dist[((size_t)b*SS + q0 + row)*SS];
    float m = -1e30f;
    f32x4 sv[16];
#pragma unroll
    for (int c = 0; c < 16; ++c) {
        int col = c16*4 + c*64;
        int4 d4 = *(const int4*)&drow[col];
        f32x4 s4;
        s4[0] = S_T[col+0][row] + qd[row][d4.x > 8 ? 8 : d4.x];
        s4[1] = S_T[col+1][row] + qd[row][d4.y > 8 ? 8 : d4.y];
        s4[2] = S_T[col+2][row] + qd[row][d4.z > 8 ? 8 : d4.z];
        s4[3] = S_T[col+3][row] + qd[row][d4.w > 8 ? 8 : d4.w];
        sv[c] = s4;
        m = fmaxf(m, fmaxf(fmaxf(s4[0], s4[1]), fmaxf(s4[2], s4[3])));
    }
#pragma unroll
    for (int o = 1; o < 16; o <<= 1) m = fmaxf(m, __shfl_xor(m, o));
    float sum = 0.f;
#pragma unroll
    for (int c = 0; c < 16; ++c) {
        int col = c16*4 + c*64;
        f32x4 p4 = sv[c];
        p4[0] = expf(p4[0]-m); p4[1] = expf(p4[1]-m);
        p4[2] = expf(p4[2]-m); p4[3] = expf(p4[3]-m);
        sum += p4[0] + p4[1] + p4[2] + p4[3];
        S_T[col+0][row] = p4[0];
        S_T[col+1][row] = p4[1];
        S_T[col+2][row] = p4[2];
        S_T[col+3][row] = p4[3];
        sv[c] = p4;
    }
#pragma unroll
    for (int o = 1; o < 16; o <<= 1) sum += __shfl_xor(sum, o);
    float inv = 1.0f / sum;
    if (c16 == 0) inv_s[row] = inv;
    __syncthreads();

    float* arow = attn + ((size_t)bh*SS + q0 + row)*SS;
#pragma unroll
    for (int c = 0; c < 16; ++c) {
        int col = c16*4 + c*64;
        f32x4 o4 = sv[c];
        o4[0] *= inv; o4[1] *= inv; o4[2] *= inv; o4[3] *= inv;
        *(f32x4*)&arow[col] = o4;
    }

    // ---- Phase C: PV (wave w -> V cols w*16..w*16+15) ----
    const short* Vh = vThi + (size_t)bh*64*SS + (size_t)(w*16 + r)*SS;
    const short* Vl = vTlo + (size_t)bh*64*SS + (size_t)(w*16 + r)*SS;
    f32x4 oacc = (f32x4){0.f,0.f,0.f,0.f};
    for (int kb = 0; kb < SS; kb += 32) {
        int k8 = kb + ko;
        bf16x8 ah, al;
#pragma unroll
        for (int e = 0; e < 8; ++e) {
            HL tt = split2(S_T[k8 + e][r]);
            ah[e] = tt.h; al[e] = tt.l;
        }
        bf16x8 vh = *(const bf16x8*)&Vh[k8];
        bf16x8 vl = *(const bf16x8*)&Vl[k8];
        oacc = __builtin_amdgcn_mfma_f32_16x16x32_bf16(ah, vh, oacc, 0, 0, 0);
        oacc = __builtin_amdgcn_mfma_f32_16x16x32_bf16(ah, vl, oacc, 0, 0, 0);
        oacc = __builtin_amdgcn_mfma_f32_16x16x32_bf16(al, vh, oacc, 0, 0, 0);
    }
#pragma unroll
    for (int rr = 0; rr < 4; ++rr) {
        int orow = g*4 + rr;
        float val = oacc[rr] * inv_s[orow];
        HL tt = split2(val);
        size_t off = ((size_t)(b*SS + q0 + orow))*512 + h*64 + w*16 + r;
        pv_hi[off] = tt.h; pv_lo[off] = tt.l;
    }
}

extern "C" void kernel_launch(void* const* d_in, const int* in_sizes, int n_in,
                              void* d_out, int out_size, void* d_ws, size_t ws_size,
                              hipStream_t stream) {
    const float* q    = (const float*)d_in[0];
    const float* k    = (const float*)d_in[1];
    const float* v    = (const float*)d_in[2];
    const int*   dist = (const int*)d_in[3];
    const float* Wq   = (const float*)d_in[4];
    const float* Wk   = (const float*)d_in[5];
    const float* Wv   = (const float*)d_in[6];
    const float* Wrpr = (const float*)d_in[7];
    const float* Wo   = (const float*)d_in[8];
    const float* ln_g = (const float*)d_in[9];
    const float* ln_b = (const float*)d_in[10];

    float* out  = (float*)d_out;                       // [B,S,D]
    float* attn = out + (size_t)BB*SS*DDIM;            // [B,H,S,S]

    const size_t NB = (size_t)BB*SS*DDIM;              // 2,097,152 elements
    short* p = (short*)d_ws;
    short* qn_hi = p;            p += NB;
    short* qn_lo = p;            p += NB;
    short* kx_hi = p;            p += NB;
    short* kx_lo = p;            p += NB;
    short* vx_hi = p;            p += NB;
    short* vx_lo = p;            p += NB;
    short* qh_hi = p;            p += NB;
    short* qh_lo = p;            p += NB;
    short* kh_hi = p;            p += NB;
    short* kh_lo = p;            p += NB;
    short* vT_hi = p;            p += NB;
    short* vT_lo = p;            p += NB;
    short* WqT_h = p;            p += 262144;
    short* WqT_l = p;            p += 262144;
    short* WkT_h = p;            p += 262144;
    short* WkT_l = p;            p += 262144;
    short* WvT_h = p;            p += 262144;
    short* WvT_l = p;            p += 262144;
    short* WoT_h = p;            p += 262144;
    short* WoT_l = p;            p += 262144;
    float* qdrp  = (float*)p;
    short* pv_hi = qn_hi;        // alias: qn dead after Q-projection
    short* pv_lo = qn_lo;

    // 1. LayerNorm(q) -> split
    ln_split<<<BB*SS, 128, 0, stream>>>(q, ln_g, ln_b, qn_hi, qn_lo);

    // 2. split k, v
    split_x<<<2048, 256, 0, stream>>>(k, kx_hi, kx_lo);
    split_x<<<2048, 256, 0, stream>>>(v, vx_hi, vx_lo);

    // 3. transpose+split weights -> [n][k]
    transW<<<dim3(8,8), 256, 0, stream>>>(Wq, WqT_h, WqT_l);
    transW<<<dim3(8,8), 256, 0, stream>>>(Wk, WkT_h, WkT_l);
    transW<<<dim3(8,8), 256, 0, stream>>>(Wv, WvT_h, WvT_l);
    transW<<<dim3(8,8), 256, 0, stream>>>(Wo, WoT_h, WoT_l);

    // 4. projections (MFMA, split-bf16); 1/sqrt(dk) folded into qh
    dim3 gp(8, 64);
    mm_gemm<0><<<gp, 256, 0, stream>>>(qn_hi, qn_lo, WqT_h, WqT_l, nullptr, qh_hi, qh_lo, nullptr, 0.125f);
    mm_gemm<0><<<gp, 256, 0, stream>>>(kx_hi, kx_lo, WkT_h, WkT_l, nullptr, kh_hi, kh_lo, nullptr, 1.0f);
    mm_gemm<2><<<gp, 256, 0, stream>>>(vx_hi, vx_lo, WvT_h, WvT_l, nullptr, vT_hi, vT_lo, nullptr, 1.0f);

    // 5. qdr
    qdr_kernel<<<128, 256, 0, stream>>>(qh_hi, qh_lo, Wrpr, qdrp);

    // 6. fused QK^T + bias + softmax + attn write + PV
    fused_attn<<<dim3(SS/QB, BB*HH), 256, 0, stream>>>(qh_hi, qh_lo, kh_hi, kh_lo,
                                                       vT_hi, vT_lo, qdrp, dist,
                                                       attn, pv_hi, pv_lo);

    // 7. output projection + residual
    mm_gemm<3><<<gp, 256, 0, stream>>>(pv_hi, pv_lo, WoT_h, WoT_l, q, nullptr, nullptr, out, 1.0f);
}

// Round 7
// 453.997 us; speedup vs baseline: 1.1464x; 1.0014x over previous
//
#include <hip/hip_runtime.h>

#define BB 4
#define SS 1024
#define DDIM 512
#define HH 8
#define NR 9
#define QB 16
#define EPSV 1e-6f

typedef __attribute__((ext_vector_type(8))) short bf16x8;
typedef __attribute__((ext_vector_type(4))) short short4v;
typedef __attribute__((ext_vector_type(4))) float f32x4;

struct HL { short h; short l; };

__device__ inline float bfv(short h) {
    union { unsigned u; float f; } b; b.u = ((unsigned)(unsigned short)h) << 16; return b.f;
}
__device__ inline HL split2(float x) {
    union { float f; unsigned u; } a; a.f = x;
    unsigned short hu = (unsigned short)(a.u >> 16);
    union { unsigned u; float f; } b; b.u = ((unsigned)hu) << 16;
    float r = x - b.f;
    union { float f; unsigned u; } c; c.f = r;
    HL o; o.h = (short)hu; o.l = (short)(c.u >> 16);
    return o;
}

// ---------- LayerNorm(q) -> split bf16 hi/lo ----------
__global__ __launch_bounds__(128) void ln_split(const float* __restrict__ q,
                                                const float* __restrict__ g,
                                                const float* __restrict__ b,
                                                short* __restrict__ yh,
                                                short* __restrict__ yl) {
    int row = blockIdx.x;
    const float* x = q + (size_t)row * DDIM;
    int t = threadIdx.x;
    float4 v = ((const float4*)x)[t];
    float s  = v.x + v.y + v.z + v.w;
    float ss = v.x*v.x + v.y*v.y + v.z*v.z + v.w*v.w;
    __shared__ float rs[128], rss[128];
    rs[t] = s; rss[t] = ss; __syncthreads();
    for (int o = 64; o > 0; o >>= 1) {
        if (t < o) { rs[t] += rs[t+o]; rss[t] += rss[t+o]; }
        __syncthreads();
    }
    float mu  = rs[0] * (1.0f/DDIM);
    float var = rss[0] * (1.0f/DDIM) - mu*mu;
    float inv = rsqrtf(var + EPSV);
    float4 gg = ((const float4*)g)[t];
    float4 bb = ((const float4*)b)[t];
    float o0 = (v.x-mu)*inv*gg.x + bb.x;
    float o1 = (v.y-mu)*inv*gg.y + bb.y;
    float o2 = (v.z-mu)*inv*gg.z + bb.z;
    float o3 = (v.w-mu)*inv*gg.w + bb.w;
    short4v h4, l4;
    HL t0 = split2(o0); h4[0] = t0.h; l4[0] = t0.l;
    HL t1 = split2(o1); h4[1] = t1.h; l4[1] = t1.l;
    HL t2 = split2(o2); h4[2] = t2.h; l4[2] = t2.l;
    HL t3 = split2(o3); h4[3] = t3.h; l4[3] = t3.l;
    *(short4v*)&yh[(size_t)row*DDIM + t*4] = h4;
    *(short4v*)&yl[(size_t)row*DDIM + t*4] = l4;
}

// ---------- split fp32 array -> bf16 hi/lo ----------
__global__ __launch_bounds__(256) void split_x(const float* __restrict__ x,
                                               short* __restrict__ xh,
                                               short* __restrict__ xl) {
    int i = blockIdx.x*256 + threadIdx.x;
    float4 v = ((const float4*)x)[i];
    short4v h4, l4;
    HL t0 = split2(v.x); h4[0] = t0.h; l4[0] = t0.l;
    HL t1 = split2(v.y); h4[1] = t1.h; l4[1] = t1.l;
    HL t2 = split2(v.z); h4[2] = t2.h; l4[2] = t2.l;
    HL t3 = split2(v.w); h4[3] = t3.h; l4[3] = t3.l;
    *(short4v*)&xh[(size_t)i*4] = h4;
    *(short4v*)&xl[(size_t)i*4] = l4;
}

// ---------- W [k][n] -> WT [n][k] bf16 hi/lo ----------
__global__ __launch_bounds__(256) void transW(const float* __restrict__ W,
                                              short* __restrict__ wth,
                                              short* __restrict__ wtl) {
    __shared__ float T[64][65];
    int n0 = blockIdx.x*64, k0 = blockIdx.y*64;
    int t = threadIdx.x;
    int kr = t >> 4, nc = (t & 15)*4;
#pragma unroll
    for (int i = 0; i < 4; ++i) {
        float4 v = *(const float4*)&W[(size_t)(k0 + kr + i*16)*DDIM + n0 + nc];
        T[nc+0][kr+i*16] = v.x;
        T[nc+1][kr+i*16] = v.y;
        T[nc+2][kr+i*16] = v.z;
        T[nc+3][kr+i*16] = v.w;
    }
    __syncthreads();
    int nr = t >> 2, kq = (t & 3)*16;
    short h8[16], l8[16];
#pragma unroll
    for (int j = 0; j < 16; ++j) {
        HL tt = split2(T[nr][kq+j]); h8[j] = tt.h; l8[j] = tt.l;
    }
    size_t base = (size_t)(n0+nr)*DDIM + k0 + kq;
#pragma unroll
    for (int j = 0; j < 2; ++j) {
        bf16x8 hv, lv;
#pragma unroll
        for (int e = 0; e < 8; ++e) { hv[e] = h8[j*8+e]; lv[e] = l8[j*8+e]; }
        *(bf16x8*)&wth[base + j*8] = hv;
        *(bf16x8*)&wtl[base + j*8] = lv;
    }
}

// ---------- merged Q/K/V projection GEMM (blockIdx.z selects) ----------
// z=0: qn@WqT -> qh head layout, scale 0.125
// z=1: kx@WkT -> kh head layout
// z=2: vx@WvT -> vT [B,H,64,S] layout
__global__ __launch_bounds__(256) void mm_gemm_qkv(
        const short* __restrict__ qnh, const short* __restrict__ qnl,
        const short* __restrict__ kxh, const short* __restrict__ kxl,
        const short* __restrict__ vxh, const short* __restrict__ vxl,
        const short* __restrict__ WqTh, const short* __restrict__ WqTl,
        const short* __restrict__ WkTh, const short* __restrict__ WkTl,
        const short* __restrict__ WvTh, const short* __restrict__ WvTl,
        short* __restrict__ qh_hi, short* __restrict__ qh_lo,
        short* __restrict__ kh_hi, short* __restrict__ kh_lo,
        short* __restrict__ vT_hi, short* __restrict__ vT_lo) {
    int z = blockIdx.z;
    const short *Ahi, *Alo, *Bhi, *Blo;
    short *o_hi, *o_lo;
    float scale = 1.0f;
    if (z == 0) { Ahi=qnh; Alo=qnl; Bhi=WqTh; Blo=WqTl; o_hi=qh_hi; o_lo=qh_lo; scale=0.125f; }
    else if (z == 1) { Ahi=kxh; Alo=kxl; Bhi=WkTh; Blo=WkTl; o_hi=kh_hi; o_lo=kh_lo; }
    else { Ahi=vxh; Alo=vxl; Bhi=WvTh; Blo=WvTl; o_hi=vT_hi; o_lo=vT_lo; }

    int n0 = blockIdx.x * 64, m0 = blockIdx.y * 64;
    int tid = threadIdx.x;
    int lane = tid & 63, w = tid >> 6;
    int wr = w >> 1, wc = w & 1;
    int r = lane & 15, ko = (lane >> 4) * 8;
    f32x4 acc[2][2] = {};
    int arow0 = m0 + wr*32 + r;
    int brow0 = n0 + wc*32 + r;
    for (int k0 = 0; k0 < 512; k0 += 32) {
        bf16x8 ah[2], al[2], bh[2], bl[2];
#pragma unroll
        for (int i = 0; i < 2; ++i) {
            size_t aoff = (size_t)(arow0 + i*16)*512 + k0 + ko;
            ah[i] = *(const bf16x8*)&Ahi[aoff];
            al[i] = *(const bf16x8*)&Alo[aoff];
            size_t boff = (size_t)(brow0 + i*16)*512 + k0 + ko;
            bh[i] = *(const bf16x8*)&Bhi[boff];
            bl[i] = *(const bf16x8*)&Blo[boff];
        }
#pragma unroll
        for (int i = 0; i < 2; ++i)
#pragma unroll
            for (int j = 0; j < 2; ++j) {
                acc[i][j] = __builtin_amdgcn_mfma_f32_16x16x32_bf16(ah[i], bh[j], acc[i][j], 0, 0, 0);
                acc[i][j] = __builtin_amdgcn_mfma_f32_16x16x32_bf16(ah[i], bl[j], acc[i][j], 0, 0, 0);
                acc[i][j] = __builtin_amdgcn_mfma_f32_16x16x32_bf16(al[i], bh[j], acc[i][j], 0, 0, 0);
            }
    }
    int rb = (lane >> 4) * 4;
    int cf = lane & 15;
#pragma unroll
    for (int i = 0; i < 2; ++i)
#pragma unroll
        for (int j = 0; j < 2; ++j)
#pragma unroll
            for (int rr = 0; rr < 4; ++rr) {
                int m = m0 + wr*32 + i*16 + rb + rr;
                int n = n0 + wc*32 + j*16 + cf;
                float v = acc[i][j][rr] * scale;
                HL tt = split2(v);
                int b = m >> 10, s = m & 1023;
                int hh = n >> 6, d = n & 63;
                size_t off;
                if (z == 2) off = ((size_t)((b*HH + hh)*64 + d))*SS + s;
                else        off = ((size_t)((b*HH + hh)*SS + s))*64 + d;
                o_hi[off] = tt.h;
                o_lo[off] = tt.l;
            }
}

// ---------- Wo GEMM: fp32 out + residual ----------
__global__ __launch_bounds__(256) void mm_gemm_o(const short* __restrict__ Ahi,
                                                 const short* __restrict__ Alo,
                                                 const short* __restrict__ Bhi,
                                                 const short* __restrict__ Blo,
                                                 const float* __restrict__ res,
                                                 float* __restrict__ o_f) {
    int n0 = blockIdx.x * 64, m0 = blockIdx.y * 64;
    int tid = threadIdx.x;
    int lane = tid & 63, w = tid >> 6;
    int wr = w >> 1, wc = w & 1;
    int r = lane & 15, ko = (lane >> 4) * 8;
    f32x4 acc[2][2] = {};
    int arow0 = m0 + wr*32 + r;
    int brow0 = n0 + wc*32 + r;
    for (int k0 = 0; k0 < 512; k0 += 32) {
        bf16x8 ah[2], al[2], bh[2], bl[2];
#pragma unroll
        for (int i = 0; i < 2; ++i) {
            size_t aoff = (size_t)(arow0 + i*16)*512 + k0 + ko;
            ah[i] = *(const bf16x8*)&Ahi[aoff];
            al[i] = *(const bf16x8*)&Alo[aoff];
            size_t boff = (size_t)(brow0 + i*16)*512 + k0 + ko;
            bh[i] = *(const bf16x8*)&Bhi[boff];
            bl[i] = *(const bf16x8*)&Blo[boff];
        }
#pragma unroll
        for (int i = 0; i < 2; ++i)
#pragma unroll
            for (int j = 0; j < 2; ++j) {
                acc[i][j] = __builtin_amdgcn_mfma_f32_16x16x32_bf16(ah[i], bh[j], acc[i][j], 0, 0, 0);
                acc[i][j] = __builtin_amdgcn_mfma_f32_16x16x32_bf16(ah[i], bl[j], acc[i][j], 0, 0, 0);
                acc[i][j] = __builtin_amdgcn_mfma_f32_16x16x32_bf16(al[i], bh[j], acc[i][j], 0, 0, 0);
            }
    }
    int rb = (lane >> 4) * 4;
    int cf = lane & 15;
#pragma unroll
    for (int i = 0; i < 2; ++i)
#pragma unroll
        for (int j = 0; j < 2; ++j)
#pragma unroll
            for (int rr = 0; rr < 4; ++rr) {
                int m = m0 + wr*32 + i*16 + rb + rr;
                int n = n0 + wc*32 + j*16 + cf;
                o_f[(size_t)m*512 + n] = acc[i][j][rr] + res[(size_t)m*512 + n];
            }
}

// ---------- qdr = qh . Wrpr -> [B,H,S,9] fp32 ----------
__global__ __launch_bounds__(256) void qdr_kernel(const short* __restrict__ qhi,
                                                  const short* __restrict__ qlo,
                                                  const float* __restrict__ Wrpr,
                                                  float* __restrict__ qdr) {
    __shared__ float w[64*NR];
    int t = threadIdx.x;
    for (int i = t; i < 64*NR; i += 256) w[i] = Wrpr[i];
    __syncthreads();
    int row = blockIdx.x*256 + t;
    const short* qh = qhi + (size_t)row*64;
    const short* ql = qlo + (size_t)row*64;
    float acc[NR] = {};
#pragma unroll
    for (int d4 = 0; d4 < 16; ++d4) {
        short4v h4 = *(const short4v*)&qh[d4*4];
        short4v l4 = *(const short4v*)&ql[d4*4];
#pragma unroll
        for (int j = 0; j < 4; ++j) {
            float x = bfv(h4[j]) + bfv(l4[j]);
            const float* wr2 = &w[(d4*4+j)*NR];
#pragma unroll
            for (int p = 0; p < NR; ++p) acc[p] += x * wr2[p];
        }
    }
#pragma unroll
    for (int p = 0; p < NR; ++p) qdr[(size_t)row*NR + p] = acc[p];
}

// ---------- fused QK^T + bias + softmax + attn-write + PV ----------
// 512 threads (8 waves) per block; block owns QB=16 q-rows x 1024 k-cols of one (b,h).
// LDS ~74.6 KB -> 2 blocks/CU = 16 waves/CU (4/SIMD) for latency hiding.
// Phase A: wave w computes k-cols w*128..w*128+127 (8 MFMA col-tiles).
// Phase B: 32 threads per q-row: bias gather + softmax + single attn write.
// Phase C: waves split k in half (wk = w>>2); partials combined via LDS PC.
__global__ __launch_bounds__(512, 4) void fused_attn(
        const short* __restrict__ qhi, const short* __restrict__ qlo,
        const short* __restrict__ khi, const short* __restrict__ klo,
        const short* __restrict__ vThi, const short* __restrict__ vTlo,
        const float* __restrict__ qdr,
        const int* __restrict__ dist,
        float* __restrict__ attn,
        short* __restrict__ pv_hi, short* __restrict__ pv_lo) {
    __shared__ float S_T[SS][QB+1];      // 1024 x 17 words = 68 KB
    __shared__ float qd[QB][NR];
    __shared__ float inv_s[QB];
    __shared__ float PC[QB][68];         // phase-C partial (k-half 1)
    int bh = blockIdx.y, b = bh >> 3, h = bh & 7;
    int q0 = blockIdx.x * QB;
    int tid = threadIdx.x, lane = tid & 63, w = tid >> 6;
    int r = lane & 15, g = lane >> 4, ko = g*8;

    if (tid < QB*NR) qd[tid/NR][tid%NR] = qdr[((size_t)bh*SS + q0)*NR + tid];

    // ---- Phase A: QK^T ----
    const short* Qh = qhi + (size_t)bh*SS*64;
    const short* Ql = qlo + (size_t)bh*SS*64;
    const short* Kh = khi + (size_t)bh*SS*64;
    const short* Kl = klo + (size_t)bh*SS*64;
    {
        f32x4 acc[8];
#pragma unroll
        for (int t2 = 0; t2 < 8; ++t2) acc[t2] = (f32x4){0.f,0.f,0.f,0.f};
#pragma unroll
        for (int ks = 0; ks < 64; ks += 32) {
            bf16x8 ah = *(const bf16x8*)&Qh[(size_t)(q0+r)*64 + ks + ko];
            bf16x8 al = *(const bf16x8*)&Ql[(size_t)(q0+r)*64 + ks + ko];
#pragma unroll
            for (int ct = 0; ct < 8; ++ct) {
                int kc = w*128 + ct*16 + r;
                bf16x8 bh2 = *(const bf16x8*)&Kh[(size_t)kc*64 + ks + ko];
                bf16x8 bl2 = *(const bf16x8*)&Kl[(size_t)kc*64 + ks + ko];
                acc[ct] = __builtin_amdgcn_mfma_f32_16x16x32_bf16(ah, bh2, acc[ct], 0, 0, 0);
                acc[ct] = __builtin_amdgcn_mfma_f32_16x16x32_bf16(ah, bl2, acc[ct], 0, 0, 0);
                acc[ct] = __builtin_amdgcn_mfma_f32_16x16x32_bf16(al, bh2, acc[ct], 0, 0, 0);
            }
        }
#pragma unroll
        for (int ct = 0; ct < 8; ++ct)
#pragma unroll
            for (int rr = 0; rr < 4; ++rr)
                S_T[w*128 + ct*16 + r][g*4 + rr] = acc[ct][rr];
    }
    __syncthreads();

    // ---- Phase B: bias + softmax + attn write (32 threads per q-row) ----
    int row = tid >> 5, c32 = tid & 31;
    const int* drow = &dist[((size_t)b*SS + q0 + row)*SS];
    float m = -1e30f;
    f32x4 sv[8];
#pragma unroll
    for (int c = 0; c < 8; ++c) {
        int col = c32*4 + c*128;
        int4 d4 = *(const int4*)&drow[col];
        f32x4 s4;
        s4[0] = S_T[col+0][row] + qd[row][d4.x > 8 ? 8 : d4.x];
        s4[1] = S_T[col+1][row] + qd[row][d4.y > 8 ? 8 : d4.y];
        s4[2] = S_T[col+2][row] + qd[row][d4.z > 8 ? 8 : d4.z];
        s4[3] = S_T[col+3][row] + qd[row][d4.w > 8 ? 8 : d4.w];
        sv[c] = s4;
        m = fmaxf(m, fmaxf(fmaxf(s4[0], s4[1]), fmaxf(s4[2], s4[3])));
    }
#pragma unroll
    for (int o = 1; o < 32; o <<= 1) m = fmaxf(m, __shfl_xor(m, o));
    float sum = 0.f;
#pragma unroll
    for (int c = 0; c < 8; ++c) {
        int col = c32*4 + c*128;
        f32x4 p4 = sv[c];
        p4[0] = expf(p4[0]-m); p4[1] = expf(p4[1]-m);
        p4[2] = expf(p4[2]-m); p4[3] = expf(p4[3]-m);
        sum += p4[0] + p4[1] + p4[2] + p4[3];
        S_T[col+0][row] = p4[0];
        S_T[col+1][row] = p4[1];
        S_T[col+2][row] = p4[2];
        S_T[col+3][row] = p4[3];
        sv[c] = p4;
    }
#pragma unroll
    for (int o = 1; o < 32; o <<= 1) sum += __shfl_xor(sum, o);
    float inv = 1.0f / sum;
    if (c32 == 0) inv_s[row] = inv;
    __syncthreads();

    float* arow = attn + ((size_t)bh*SS + q0 + row)*SS;
#pragma unroll
    for (int c = 0; c < 8; ++c) {
        int col = c32*4 + c*128;
        f32x4 o4 = sv[c];
        o4[0] *= inv; o4[1] *= inv; o4[2] *= inv; o4[3] *= inv;
        *(f32x4*)&arow[col] = o4;
    }

    // ---- Phase C: PV; wd = d-tile, wk = k-half ----
    int wd = w & 3, wk = w >> 2;
    const short* Vh = vThi + (size_t)bh*64*SS + (size_t)(wd*16 + r)*SS;
    const short* Vl = vTlo + (size_t)bh*64*SS + (size_t)(wd*16 + r)*SS;
    f32x4 oacc = (f32x4){0.f,0.f,0.f,0.f};
    for (int kbi = 0; kbi < 16; ++kbi) {
        int k8 = wk*512 + kbi*32 + ko;
        bf16x8 ah, al;
#pragma unroll
        for (int e = 0; e < 8; ++e) {
            HL tt = split2(S_T[k8 + e][r]);
            ah[e] = tt.h; al[e] = tt.l;
        }
        bf16x8 vh = *(const bf16x8*)&Vh[k8];
        bf16x8 vl = *(const bf16x8*)&Vl[k8];
        oacc = __builtin_amdgcn_mfma_f32_16x16x32_bf16(ah, vh, oacc, 0, 0, 0);
        oacc = __builtin_amdgcn_mfma_f32_16x16x32_bf16(ah, vl, oacc, 0, 0, 0);
        oacc = __builtin_amdgcn_mfma_f32_16x16x32_bf16(al, vh, oacc, 0, 0, 0);
    }
    if (wk == 1) {
#pragma unroll
        for (int rr = 0; rr < 4; ++rr) PC[g*4 + rr][wd*16 + r] = oacc[rr];
    }
    __syncthreads();
    if (wk == 0) {
#pragma unroll
        for (int rr = 0; rr < 4; ++rr) {
            int orow = g*4 + rr;
            float val = (oacc[rr] + PC[orow][wd*16 + r]) * inv_s[orow];
            HL tt = split2(val);
            size_t off = ((size_t)(b*SS + q0 + orow))*512 + h*64 + wd*16 + r;
            pv_hi[off] = tt.h; pv_lo[off] = tt.l;
        }
    }
}

extern "C" void kernel_launch(void* const* d_in, const int* in_sizes, int n_in,
                              void* d_out, int out_size, void* d_ws, size_t ws_size,
                              hipStream_t stream) {
    const float* q    = (const float*)d_in[0];
    const float* k    = (const float*)d_in[1];
    const float* v    = (const float*)d_in[2];
    const int*   dist = (const int*)d_in[3];
    const float* Wq   = (const float*)d_in[4];
    const float* Wk   = (const float*)d_in[5];
    const float* Wv   = (const float*)d_in[6];
    const float* Wrpr = (const float*)d_in[7];
    const float* Wo   = (const float*)d_in[8];
    const float* ln_g = (const float*)d_in[9];
    const float* ln_b = (const float*)d_in[10];

    float* out  = (float*)d_out;                       // [B,S,D]
    float* attn = out + (size_t)BB*SS*DDIM;            // [B,H,S,S]

    const size_t NB = (size_t)BB*SS*DDIM;              // 2,097,152 elements
    short* p = (short*)d_ws;
    short* qn_hi = p;            p += NB;
    short* qn_lo = p;            p += NB;
    short* kx_hi = p;            p += NB;
    short* kx_lo = p;            p += NB;
    short* vx_hi = p;            p += NB;
    short* vx_lo = p;            p += NB;
    short* qh_hi = p;            p += NB;
    short* qh_lo = p;            p += NB;
    short* kh_hi = p;            p += NB;
    short* kh_lo = p;            p += NB;
    short* vT_hi = p;            p += NB;
    short* vT_lo = p;            p += NB;
    short* WqT_h = p;            p += 262144;
    short* WqT_l = p;            p += 262144;
    short* WkT_h = p;            p += 262144;
    short* WkT_l = p;            p += 262144;
    short* WvT_h = p;            p += 262144;
    short* WvT_l = p;            p += 262144;
    short* WoT_h = p;            p += 262144;
    short* WoT_l = p;            p += 262144;
    float* qdrp  = (float*)p;
    short* pv_hi = qn_hi;        // alias: qn dead after Q-projection
    short* pv_lo = qn_lo;

    // 1. LayerNorm(q) -> split
    ln_split<<<BB*SS, 128, 0, stream>>>(q, ln_g, ln_b, qn_hi, qn_lo);

    // 2. split k, v
    split_x<<<2048, 256, 0, stream>>>(k, kx_hi, kx_lo);
    split_x<<<2048, 256, 0, stream>>>(v, vx_hi, vx_lo);

    // 3. transpose+split weights -> [n][k]
    transW<<<dim3(8,8), 256, 0, stream>>>(Wq, WqT_h, WqT_l);
    transW<<<dim3(8,8), 256, 0, stream>>>(Wk, WkT_h, WkT_l);
    transW<<<dim3(8,8), 256, 0, stream>>>(Wv, WvT_h, WvT_l);
    transW<<<dim3(8,8), 256, 0, stream>>>(Wo, WoT_h, WoT_l);

    // 4. merged Q/K/V projections (one dispatch, 1536 blocks)
    mm_gemm_qkv<<<dim3(8, 64, 3), 256, 0, stream>>>(
        qn_hi, qn_lo, kx_hi, kx_lo, vx_hi, vx_lo,
        WqT_h, WqT_l, WkT_h, WkT_l, WvT_h, WvT_l,
        qh_hi, qh_lo, kh_hi, kh_lo, vT_hi, vT_lo);

    // 5. qdr
    qdr_kernel<<<128, 256, 0, stream>>>(qh_hi, qh_lo, Wrpr, qdrp);

    // 6. fused QK^T + bias + softmax + attn write + PV (512 thr, 2 blocks/CU)
    fused_attn<<<dim3(SS/QB, BB*HH), 512, 0, stream>>>(qh_hi, qh_lo, kh_hi, kh_lo,
                                                       vT_hi, vT_lo, qdrp, dist,
                                                       attn, pv_hi, pv_lo);

    // 7. output projection + residual
    mm_gemm_o<<<dim3(8, 64), 256, 0, stream>>>(pv_hi, pv_lo, WoT_h, WoT_l, q, out);
}

// Round 8
// 384.893 us; speedup vs baseline: 1.3522x; 1.1795x over previous
//
#include <hip/hip_runtime.h>

#define BB 4
#define SS 1024
#define DDIM 512
#define HH 8
#define NR 9
#define QB 16
#define EPSV 1e-6f

typedef __attribute__((ext_vector_type(8))) short bf16x8;
typedef __attribute__((ext_vector_type(4))) short short4v;
typedef __attribute__((ext_vector_type(4))) float f32x4;

struct HL { short h; short l; };

__device__ inline float bfv(short h) {
    union { unsigned u; float f; } b; b.u = ((unsigned)(unsigned short)h) << 16; return b.f;
}
__device__ inline HL split2(float x) {
    union { float f; unsigned u; } a; a.f = x;
    unsigned short hu = (unsigned short)(a.u >> 16);
    union { unsigned u; float f; } b; b.u = ((unsigned)hu) << 16;
    float r = x - b.f;
    union { float f; unsigned u; } c; c.f = r;
    HL o; o.h = (short)hu; o.l = (short)(c.u >> 16);
    return o;
}

// ---------- LayerNorm(q) -> split bf16 hi/lo ----------
__global__ __launch_bounds__(128) void ln_split(const float* __restrict__ q,
                                                const float* __restrict__ g,
                                                const float* __restrict__ b,
                                                short* __restrict__ yh,
                                                short* __restrict__ yl) {
    int row = blockIdx.x;
    const float* x = q + (size_t)row * DDIM;
    int t = threadIdx.x;
    float4 v = ((const float4*)x)[t];
    float s  = v.x + v.y + v.z + v.w;
    float ss = v.x*v.x + v.y*v.y + v.z*v.z + v.w*v.w;
    __shared__ float rs[128], rss[128];
    rs[t] = s; rss[t] = ss; __syncthreads();
    for (int o = 64; o > 0; o >>= 1) {
        if (t < o) { rs[t] += rs[t+o]; rss[t] += rss[t+o]; }
        __syncthreads();
    }
    float mu  = rs[0] * (1.0f/DDIM);
    float var = rss[0] * (1.0f/DDIM) - mu*mu;
    float inv = rsqrtf(var + EPSV);
    float4 gg = ((const float4*)g)[t];
    float4 bb = ((const float4*)b)[t];
    float o0 = (v.x-mu)*inv*gg.x + bb.x;
    float o1 = (v.y-mu)*inv*gg.y + bb.y;
    float o2 = (v.z-mu)*inv*gg.z + bb.z;
    float o3 = (v.w-mu)*inv*gg.w + bb.w;
    short4v h4, l4;
    HL t0 = split2(o0); h4[0] = t0.h; l4[0] = t0.l;
    HL t1 = split2(o1); h4[1] = t1.h; l4[1] = t1.l;
    HL t2 = split2(o2); h4[2] = t2.h; l4[2] = t2.l;
    HL t3 = split2(o3); h4[3] = t3.h; l4[3] = t3.l;
    *(short4v*)&yh[(size_t)row*DDIM + t*4] = h4;
    *(short4v*)&yl[(size_t)row*DDIM + t*4] = l4;
}

// ---------- split fp32 array -> bf16 hi/lo ----------
__global__ __launch_bounds__(256) void split_x(const float* __restrict__ x,
                                               short* __restrict__ xh,
                                               short* __restrict__ xl) {
    int i = blockIdx.x*256 + threadIdx.x;
    float4 v = ((const float4*)x)[i];
    short4v h4, l4;
    HL t0 = split2(v.x); h4[0] = t0.h; l4[0] = t0.l;
    HL t1 = split2(v.y); h4[1] = t1.h; l4[1] = t1.l;
    HL t2 = split2(v.z); h4[2] = t2.h; l4[2] = t2.l;
    HL t3 = split2(v.w); h4[3] = t3.h; l4[3] = t3.l;
    *(short4v*)&xh[(size_t)i*4] = h4;
    *(short4v*)&xl[(size_t)i*4] = l4;
}

// ---------- W [k][n] -> WT [n][k] bf16 hi/lo ----------
__global__ __launch_bounds__(256) void transW(const float* __restrict__ W,
                                              short* __restrict__ wth,
                                              short* __restrict__ wtl) {
    __shared__ float T[64][65];
    int n0 = blockIdx.x*64, k0 = blockIdx.y*64;
    int t = threadIdx.x;
    int kr = t >> 4, nc = (t & 15)*4;
#pragma unroll
    for (int i = 0; i < 4; ++i) {
        float4 v = *(const float4*)&W[(size_t)(k0 + kr + i*16)*DDIM + n0 + nc];
        T[nc+0][kr+i*16] = v.x;
        T[nc+1][kr+i*16] = v.y;
        T[nc+2][kr+i*16] = v.z;
        T[nc+3][kr+i*16] = v.w;
    }
    __syncthreads();
    int nr = t >> 2, kq = (t & 3)*16;
    short h8[16], l8[16];
#pragma unroll
    for (int j = 0; j < 16; ++j) {
        HL tt = split2(T[nr][kq+j]); h8[j] = tt.h; l8[j] = tt.l;
    }
    size_t base = (size_t)(n0+nr)*DDIM + k0 + kq;
#pragma unroll
    for (int j = 0; j < 2; ++j) {
        bf16x8 hv, lv;
#pragma unroll
        for (int e = 0; e < 8; ++e) { hv[e] = h8[j*8+e]; lv[e] = l8[j*8+e]; }
        *(bf16x8*)&wth[base + j*8] = hv;
        *(bf16x8*)&wtl[base + j*8] = lv;
    }
}

// ---------- merged Q/K/V projection GEMM, LDS-staged ----------
// z=0: qn@WqT -> qh head layout, scale 0.125; z=1: k; z=2: v -> vT [B,H,64,S]
__global__ __launch_bounds__(256) void mm_gemm_qkv(
        const short* __restrict__ qnh, const short* __restrict__ qnl,
        const short* __restrict__ kxh, const short* __restrict__ kxl,
        const short* __restrict__ vxh, const short* __restrict__ vxl,
        const short* __restrict__ WqTh, const short* __restrict__ WqTl,
        const short* __restrict__ WkTh, const short* __restrict__ WkTl,
        const short* __restrict__ WvTh, const short* __restrict__ WvTl,
        short* __restrict__ qh_hi, short* __restrict__ qh_lo,
        short* __restrict__ kh_hi, short* __restrict__ kh_lo,
        short* __restrict__ vT_hi, short* __restrict__ vT_lo) {
    __shared__ short As_h[64][72], As_l[64][72], Bs_h[64][72], Bs_l[64][72];
    int z = blockIdx.z;
    const short *Ahi, *Alo, *Bhi, *Blo;
    short *o_hi, *o_lo;
    float scale = 1.0f;
    if (z == 0) { Ahi=qnh; Alo=qnl; Bhi=WqTh; Blo=WqTl; o_hi=qh_hi; o_lo=qh_lo; scale=0.125f; }
    else if (z == 1) { Ahi=kxh; Alo=kxl; Bhi=WkTh; Blo=WkTl; o_hi=kh_hi; o_lo=kh_lo; }
    else { Ahi=vxh; Alo=vxl; Bhi=WvTh; Blo=WvTl; o_hi=vT_hi; o_lo=vT_lo; }

    int n0 = blockIdx.x * 64, m0 = blockIdx.y * 64;
    int tid = threadIdx.x;
    int lane = tid & 63, w = tid >> 6;
    int wr = w >> 1, wc = w & 1;
    int r = lane & 15, ko = (lane >> 4) * 8;
    int lrow = tid >> 2, lcol = (tid & 3) * 16;
    const short* Ah0 = &Ahi[(size_t)(m0+lrow)*512 + lcol];
    const short* Al0 = &Alo[(size_t)(m0+lrow)*512 + lcol];
    const short* Bh0 = &Bhi[(size_t)(n0+lrow)*512 + lcol];
    const short* Bl0 = &Blo[(size_t)(n0+lrow)*512 + lcol];
    bf16x8 rah[2], ral[2], rbh[2], rbl[2];
#define LOADREG(K) do { \
        rah[0]=*(const bf16x8*)&Ah0[K]; rah[1]=*(const bf16x8*)&Ah0[(K)+8]; \
        ral[0]=*(const bf16x8*)&Al0[K]; ral[1]=*(const bf16x8*)&Al0[(K)+8]; \
        rbh[0]=*(const bf16x8*)&Bh0[K]; rbh[1]=*(const bf16x8*)&Bh0[(K)+8]; \
        rbl[0]=*(const bf16x8*)&Bl0[K]; rbl[1]=*(const bf16x8*)&Bl0[(K)+8]; } while(0)
    LOADREG(0);
    f32x4 acc[2][2] = {};
    for (int k0 = 0; k0 < 512; k0 += 64) {
        __syncthreads();
        *(bf16x8*)&As_h[lrow][lcol] = rah[0]; *(bf16x8*)&As_h[lrow][lcol+8] = rah[1];
        *(bf16x8*)&As_l[lrow][lcol] = ral[0]; *(bf16x8*)&As_l[lrow][lcol+8] = ral[1];
        *(bf16x8*)&Bs_h[lrow][lcol] = rbh[0]; *(bf16x8*)&Bs_h[lrow][lcol+8] = rbh[1];
        *(bf16x8*)&Bs_l[lrow][lcol] = rbl[0]; *(bf16x8*)&Bs_l[lrow][lcol+8] = rbl[1];
        __syncthreads();
        if (k0 < 448) LOADREG(k0 + 64);
#pragma unroll
        for (int ks = 0; ks < 64; ks += 32) {
            bf16x8 ah[2], al[2], bh2[2], bl2[2];
#pragma unroll
            for (int i = 0; i < 2; ++i) {
                ah[i]  = *(const bf16x8*)&As_h[wr*32 + i*16 + r][ks + ko];
                al[i]  = *(const bf16x8*)&As_l[wr*32 + i*16 + r][ks + ko];
                bh2[i] = *(const bf16x8*)&Bs_h[wc*32 + i*16 + r][ks + ko];
                bl2[i] = *(const bf16x8*)&Bs_l[wc*32 + i*16 + r][ks + ko];
            }
#pragma unroll
            for (int i = 0; i < 2; ++i)
#pragma unroll
                for (int j = 0; j < 2; ++j) {
                    acc[i][j] = __builtin_amdgcn_mfma_f32_16x16x32_bf16(ah[i], bh2[j], acc[i][j], 0, 0, 0);
                    acc[i][j] = __builtin_amdgcn_mfma_f32_16x16x32_bf16(ah[i], bl2[j], acc[i][j], 0, 0, 0);
                    acc[i][j] = __builtin_amdgcn_mfma_f32_16x16x32_bf16(al[i], bh2[j], acc[i][j], 0, 0, 0);
                }
        }
    }
    int rb = (lane >> 4) * 4;
    int cf = lane & 15;
#pragma unroll
    for (int i = 0; i < 2; ++i)
#pragma unroll
        for (int j = 0; j < 2; ++j)
#pragma unroll
            for (int rr = 0; rr < 4; ++rr) {
                int m = m0 + wr*32 + i*16 + rb + rr;
                int n = n0 + wc*32 + j*16 + cf;
                float v = acc[i][j][rr] * scale;
                HL tt = split2(v);
                int b = m >> 10, s = m & 1023;
                int hh = n >> 6, d = n & 63;
                size_t off;
                if (z == 2) off = ((size_t)((b*HH + hh)*64 + d))*SS + s;
                else        off = ((size_t)((b*HH + hh)*SS + s))*64 + d;
                o_hi[off] = tt.h;
                o_lo[off] = tt.l;
            }
}

// ---------- Wo GEMM, LDS-staged: fp32 out + residual ----------
__global__ __launch_bounds__(256) void mm_gemm_o(const short* __restrict__ Ahi,
                                                 const short* __restrict__ Alo,
                                                 const short* __restrict__ Bhi,
                                                 const short* __restrict__ Blo,
                                                 const float* __restrict__ res,
                                                 float* __restrict__ o_f) {
    __shared__ short As_h[64][72], As_l[64][72], Bs_h[64][72], Bs_l[64][72];
    int n0 = blockIdx.x * 64, m0 = blockIdx.y * 64;
    int tid = threadIdx.x;
    int lane = tid & 63, w = tid >> 6;
    int wr = w >> 1, wc = w & 1;
    int r = lane & 15, ko = (lane >> 4) * 8;
    int lrow = tid >> 2, lcol = (tid & 3) * 16;
    const short* Ah0 = &Ahi[(size_t)(m0+lrow)*512 + lcol];
    const short* Al0 = &Alo[(size_t)(m0+lrow)*512 + lcol];
    const short* Bh0 = &Bhi[(size_t)(n0+lrow)*512 + lcol];
    const short* Bl0 = &Blo[(size_t)(n0+lrow)*512 + lcol];
    bf16x8 rah[2], ral[2], rbh[2], rbl[2];
    LOADREG(0);
    f32x4 acc[2][2] = {};
    for (int k0 = 0; k0 < 512; k0 += 64) {
        __syncthreads();
        *(bf16x8*)&As_h[lrow][lcol] = rah[0]; *(bf16x8*)&As_h[lrow][lcol+8] = rah[1];
        *(bf16x8*)&As_l[lrow][lcol] = ral[0]; *(bf16x8*)&As_l[lrow][lcol+8] = ral[1];
        *(bf16x8*)&Bs_h[lrow][lcol] = rbh[0]; *(bf16x8*)&Bs_h[lrow][lcol+8] = rbh[1];
        *(bf16x8*)&Bs_l[lrow][lcol] = rbl[0]; *(bf16x8*)&Bs_l[lrow][lcol+8] = rbl[1];
        __syncthreads();
        if (k0 < 448) LOADREG(k0 + 64);
#pragma unroll
        for (int ks = 0; ks < 64; ks += 32) {
            bf16x8 ah[2], al[2], bh2[2], bl2[2];
#pragma unroll
            for (int i = 0; i < 2; ++i) {
                ah[i]  = *(const bf16x8*)&As_h[wr*32 + i*16 + r][ks + ko];
                al[i]  = *(const bf16x8*)&As_l[wr*32 + i*16 + r][ks + ko];
                bh2[i] = *(const bf16x8*)&Bs_h[wc*32 + i*16 + r][ks + ko];
                bl2[i] = *(const bf16x8*)&Bs_l[wc*32 + i*16 + r][ks + ko];
            }
#pragma unroll
            for (int i = 0; i < 2; ++i)
#pragma unroll
                for (int j = 0; j < 2; ++j) {
                    acc[i][j] = __builtin_amdgcn_mfma_f32_16x16x32_bf16(ah[i], bh2[j], acc[i][j], 0, 0, 0);
                    acc[i][j] = __builtin_amdgcn_mfma_f32_16x16x32_bf16(ah[i], bl2[j], acc[i][j], 0, 0, 0);
                    acc[i][j] = __builtin_amdgcn_mfma_f32_16x16x32_bf16(al[i], bh2[j], acc[i][j], 0, 0, 0);
                }
        }
    }
    int rb = (lane >> 4) * 4;
    int cf = lane & 15;
#pragma unroll
    for (int i = 0; i < 2; ++i)
#pragma unroll
        for (int j = 0; j < 2; ++j)
#pragma unroll
            for (int rr = 0; rr < 4; ++rr) {
                int m = m0 + wr*32 + i*16 + rb + rr;
                int n = n0 + wc*32 + j*16 + cf;
                o_f[(size_t)m*512 + n] = acc[i][j][rr] + res[(size_t)m*512 + n];
            }
}

// ---------- qdr = qh . Wrpr -> [B,H,S,9] fp32 ----------
__global__ __launch_bounds__(256) void qdr_kernel(const short* __restrict__ qhi,
                                                  const short* __restrict__ qlo,
                                                  const float* __restrict__ Wrpr,
                                                  float* __restrict__ qdr) {
    __shared__ float w[64*NR];
    int t = threadIdx.x;
    for (int i = t; i < 64*NR; i += 256) w[i] = Wrpr[i];
    __syncthreads();
    int row = blockIdx.x*256 + t;
    const short* qh = qhi + (size_t)row*64;
    const short* ql = qlo + (size_t)row*64;
    float acc[NR] = {};
#pragma unroll
    for (int d4 = 0; d4 < 16; ++d4) {
        short4v h4 = *(const short4v*)&qh[d4*4];
        short4v l4 = *(const short4v*)&ql[d4*4];
#pragma unroll
        for (int j = 0; j < 4; ++j) {
            float x = bfv(h4[j]) + bfv(l4[j]);
            const float* wr2 = &w[(d4*4+j)*NR];
#pragma unroll
            for (int p = 0; p < NR; ++p) acc[p] += x * wr2[p];
        }
    }
#pragma unroll
    for (int p = 0; p < NR; ++p) qdr[(size_t)row*NR + p] = acc[p];
}

// ---------- fused QK^T + bias + softmax + attn-write + PV ----------
// 512 threads (8 waves); block owns QB=16 q-rows x 1024 k-cols of one (b,h).
// smem buffer aliased: Phase A/B logits as f32 S_T[col][17-row], then (after a
// barrier) Phase B rewrites it as bf16 P_hi/P_lo[16][1032] so Phase C reads its
// MFMA A-fragments as ds_read_b128 (was: 8 scalar reads + 8 split2 per step).
__global__ __launch_bounds__(512, 4) void fused_attn(
        const short* __restrict__ qhi, const short* __restrict__ qlo,
        const short* __restrict__ khi, const short* __restrict__ klo,
        const short* __restrict__ vThi, const short* __restrict__ vTlo,
        const float* __restrict__ qdr,
        const int* __restrict__ dist,
        float* __restrict__ attn,
        short* __restrict__ pv_hi, short* __restrict__ pv_lo) {
    __shared__ float smem[SS*(QB+1)];    // 69632 B, aliased (S_T then P_hi/P_lo)
    __shared__ float qd[QB][NR];
    __shared__ float inv_s[QB];
    __shared__ float PC[QB][68];
    short (*P_h)[1032] = (short(*)[1032])smem;
    short (*P_l)[1032] = (short(*)[1032])((char*)smem + 16*1032*2);
    int bh = blockIdx.y, b = bh >> 3, h = bh & 7;
    int q0 = blockIdx.x * QB;
    int tid = threadIdx.x, lane = tid & 63, w = tid >> 6;
    int r = lane & 15, g = lane >> 4, ko = g*8;

    if (tid < QB*NR) qd[tid/NR][tid%NR] = qdr[((size_t)bh*SS + q0)*NR + tid];

    // ---- Phase A: QK^T -> S_T (f32, transposed: smem[kcol*17 + qrow]) ----
    const short* Qh = qhi + (size_t)bh*SS*64;
    const short* Ql = qlo + (size_t)bh*SS*64;
    const short* Kh = khi + (size_t)bh*SS*64;
    const short* Kl = klo + (size_t)bh*SS*64;
    {
        f32x4 acc[8];
#pragma unroll
        for (int t2 = 0; t2 < 8; ++t2) acc[t2] = (f32x4){0.f,0.f,0.f,0.f};
#pragma unroll
        for (int ks = 0; ks < 64; ks += 32) {
            bf16x8 ah = *(const bf16x8*)&Qh[(size_t)(q0+r)*64 + ks + ko];
            bf16x8 al = *(const bf16x8*)&Ql[(size_t)(q0+r)*64 + ks + ko];
#pragma unroll
            for (int ct = 0; ct < 8; ++ct) {
                int kc = w*128 + ct*16 + r;
                bf16x8 bh2 = *(const bf16x8*)&Kh[(size_t)kc*64 + ks + ko];
                bf16x8 bl2 = *(const bf16x8*)&Kl[(size_t)kc*64 + ks + ko];
                acc[ct] = __builtin_amdgcn_mfma_f32_16x16x32_bf16(ah, bh2, acc[ct], 0, 0, 0);
                acc[ct] = __builtin_amdgcn_mfma_f32_16x16x32_bf16(ah, bl2, acc[ct], 0, 0, 0);
                acc[ct] = __builtin_amdgcn_mfma_f32_16x16x32_bf16(al, bh2, acc[ct], 0, 0, 0);
            }
        }
#pragma unroll
        for (int ct = 0; ct < 8; ++ct)
#pragma unroll
            for (int rr = 0; rr < 4; ++rr)
                smem[(w*128 + ct*16 + r)*17 + g*4 + rr] = acc[ct][rr];
    }
    __syncthreads();

    // ---- Phase B: bias gather -> regs; barrier; softmax; write P (bf16) + attn ----
    int row = tid >> 5, c32 = tid & 31;
    const int* drow = &dist[((size_t)b*SS + q0 + row)*SS];
    float m = -1e30f;
    f32x4 sv[8];
#pragma unroll
    for (int c = 0; c < 8; ++c) {
        int col = c32*4 + c*128;
        int4 d4 = *(const int4*)&drow[col];
        f32x4 s4;
        s4[0] = smem[(col+0)*17 + row] + qd[row][d4.x > 8 ? 8 : d4.x];
        s4[1] = smem[(col+1)*17 + row] + qd[row][d4.y > 8 ? 8 : d4.y];
        s4[2] = smem[(col+2)*17 + row] + qd[row][d4.z > 8 ? 8 : d4.z];
        s4[3] = smem[(col+3)*17 + row] + qd[row][d4.w > 8 ? 8 : d4.w];
        sv[c] = s4;
        m = fmaxf(m, fmaxf(fmaxf(s4[0], s4[1]), fmaxf(s4[2], s4[3])));
    }
    __syncthreads();            // all S_T reads done -> smem reusable as P
#pragma unroll
    for (int o = 1; o < 32; o <<= 1) m = fmaxf(m, __shfl_xor(m, o));
    float sum = 0.f;
#pragma unroll
    for (int c = 0; c < 8; ++c) {
        int col = c32*4 + c*128;
        f32x4 p4 = sv[c];
        p4[0] = expf(p4[0]-m); p4[1] = expf(p4[1]-m);
        p4[2] = expf(p4[2]-m); p4[3] = expf(p4[3]-m);
        sum += p4[0] + p4[1] + p4[2] + p4[3];
        short4v ph, pl;
        HL t0 = split2(p4[0]); ph[0] = t0.h; pl[0] = t0.l;
        HL t1 = split2(p4[1]); ph[1] = t1.h; pl[1] = t1.l;
        HL t2 = split2(p4[2]); ph[2] = t2.h; pl[2] = t2.l;
        HL t3 = split2(p4[3]); ph[3] = t3.h; pl[3] = t3.l;
        *(short4v*)&P_h[row][col] = ph;
        *(short4v*)&P_l[row][col] = pl;
        sv[c] = p4;
    }
#pragma unroll
    for (int o = 1; o < 32; o <<= 1) sum += __shfl_xor(sum, o);
    float inv = 1.0f / sum;
    if (c32 == 0) inv_s[row] = inv;

    float* arow = attn + ((size_t)bh*SS + q0 + row)*SS;
#pragma unroll
    for (int c = 0; c < 8; ++c) {
        int col = c32*4 + c*128;
        f32x4 o4 = sv[c];
        o4[0] *= inv; o4[1] *= inv; o4[2] *= inv; o4[3] *= inv;
        *(f32x4*)&arow[col] = o4;
    }
    __syncthreads();            // P complete before Phase C reads

    // ---- Phase C: PV from bf16 P (b128 reads); wd = d-tile, wk = k-half ----
    int wd = w & 3, wk = w >> 2;
    const short* Vh = vThi + (size_t)bh*64*SS + (size_t)(wd*16 + r)*SS;
    const short* Vl = vTlo + (size_t)bh*64*SS + (size_t)(wd*16 + r)*SS;
    f32x4 oacc = (f32x4){0.f,0.f,0.f,0.f};
    for (int kbi = 0; kbi < 16; ++kbi) {
        int k8 = wk*512 + kbi*32 + ko;
        bf16x8 ah = *(const bf16x8*)&P_h[r][k8];
        bf16x8 al = *(const bf16x8*)&P_l[r][k8];
        bf16x8 vh = *(const bf16x8*)&Vh[k8];
        bf16x8 vl = *(const bf16x8*)&Vl[k8];
        oacc = __builtin_amdgcn_mfma_f32_16x16x32_bf16(ah, vh, oacc, 0, 0, 0);
        oacc = __builtin_amdgcn_mfma_f32_16x16x32_bf16(ah, vl, oacc, 0, 0, 0);
        oacc = __builtin_amdgcn_mfma_f32_16x16x32_bf16(al, vh, oacc, 0, 0, 0);
    }
    if (wk == 1) {
#pragma unroll
        for (int rr = 0; rr < 4; ++rr) PC[g*4 + rr][wd*16 + r] = oacc[rr];
    }
    __syncthreads();
    if (wk == 0) {
#pragma unroll
        for (int rr = 0; rr < 4; ++rr) {
            int orow = g*4 + rr;
            float val = (oacc[rr] + PC[orow][wd*16 + r]) * inv_s[orow];
            HL tt = split2(val);
            size_t off = ((size_t)(b*SS + q0 + orow))*512 + h*64 + wd*16 + r;
            pv_hi[off] = tt.h; pv_lo[off] = tt.l;
        }
    }
}

extern "C" void kernel_launch(void* const* d_in, const int* in_sizes, int n_in,
                              void* d_out, int out_size, void* d_ws, size_t ws_size,
                              hipStream_t stream) {
    const float* q    = (const float*)d_in[0];
    const float* k    = (const float*)d_in[1];
    const float* v    = (const float*)d_in[2];
    const int*   dist = (const int*)d_in[3];
    const float* Wq   = (const float*)d_in[4];
    const float* Wk   = (const float*)d_in[5];
    const float* Wv   = (const float*)d_in[6];
    const float* Wrpr = (const float*)d_in[7];
    const float* Wo   = (const float*)d_in[8];
    const float* ln_g = (const float*)d_in[9];
    const float* ln_b = (const float*)d_in[10];

    float* out  = (float*)d_out;                       // [B,S,D]
    float* attn = out + (size_t)BB*SS*DDIM;            // [B,H,S,S]

    const size_t NB = (size_t)BB*SS*DDIM;              // 2,097,152 elements
    short* p = (short*)d_ws;
    short* qn_hi = p;            p += NB;
    short* qn_lo = p;            p += NB;
    short* kx_hi = p;            p += NB;
    short* kx_lo = p;            p += NB;
    short* vx_hi = p;            p += NB;
    short* vx_lo = p;            p += NB;
    short* qh_hi = p;            p += NB;
    short* qh_lo = p;            p += NB;
    short* kh_hi = p;            p += NB;
    short* kh_lo = p;            p += NB;
    short* vT_hi = p;            p += NB;
    short* vT_lo = p;            p += NB;
    short* WqT_h = p;            p += 262144;
    short* WqT_l = p;            p += 262144;
    short* WkT_h = p;            p += 262144;
    short* WkT_l = p;            p += 262144;
    short* WvT_h = p;            p += 262144;
    short* WvT_l = p;            p += 262144;
    short* WoT_h = p;            p += 262144;
    short* WoT_l = p;            p += 262144;
    float* qdrp  = (float*)p;
    short* pv_hi = qn_hi;        // alias: qn dead after Q-projection
    short* pv_lo = qn_lo;

    // 1. LayerNorm(q) -> split
    ln_split<<<BB*SS, 128, 0, stream>>>(q, ln_g, ln_b, qn_hi, qn_lo);

    // 2. split k, v
    split_x<<<2048, 256, 0, stream>>>(k, kx_hi, kx_lo);
    split_x<<<2048, 256, 0, stream>>>(v, vx_hi, vx_lo);

    // 3. transpose+split weights -> [n][k]
    transW<<<dim3(8,8), 256, 0, stream>>>(Wq, WqT_h, WqT_l);
    transW<<<dim3(8,8), 256, 0, stream>>>(Wk, WkT_h, WkT_l);
    transW<<<dim3(8,8), 256, 0, stream>>>(Wv, WvT_h, WvT_l);
    transW<<<dim3(8,8), 256, 0, stream>>>(Wo, WoT_h, WoT_l);

    // 4. merged Q/K/V projections (LDS-staged)
    mm_gemm_qkv<<<dim3(8, 64, 3), 256, 0, stream>>>(
        qn_hi, qn_lo, kx_hi, kx_lo, vx_hi, vx_lo,
        WqT_h, WqT_l, WkT_h, WkT_l, WvT_h, WvT_l,
        qh_hi, qh_lo, kh_hi, kh_lo, vT_hi, vT_lo);

    // 5. qdr
    qdr_kernel<<<128, 256, 0, stream>>>(qh_hi, qh_lo, Wrpr, qdrp);

    // 6. fused QK^T + bias + softmax + attn write + PV
    fused_attn<<<dim3(SS/QB, BB*HH), 512, 0, stream>>>(qh_hi, qh_lo, kh_hi, kh_lo,
                                                       vT_hi, vT_lo, qdrp, dist,
                                                       attn, pv_hi, pv_lo);

    // 7. output projection + residual (LDS-staged)
    mm_gemm_o<<<dim3(8, 64), 256, 0, stream>>>(pv_hi, pv_lo, WoT_h, WoT_l, q, out);
}